// Round 1
// baseline (1756.970 us; speedup 1.0000x reference)
//
#include <hip/hip_runtime.h>
#include <stdint.h>

// Problem dims (fixed by reference setup_inputs):
//   x: [T=4, B=32, C=196, N=768] fp32; w1,w2,w3: [768,768] fp32
#define T_STEPS 4
#define BC      6272            // B*C = 32*196
#define NDIM    768
#define TBC     (T_STEPS*BC)    // 25088 rows total
#define BCN     (BC*NDIM)       // 4816896

// ---------------------------------------------------------------------------
// Kernel A: s = lif(x), fp64 recursion over t. Output packed: one u32 per
// (bc,n); byte t holds spike bit for timestep t.
// ---------------------------------------------------------------------------
__global__ __launch_bounds__(256) void lif_x_kernel(const float* __restrict__ x,
                                                    uint32_t* __restrict__ sp) {
    int idx = blockIdx.x * 256 + threadIdx.x;      // (bc,n) flat, [0, BCN)
    double v = 0.0;
    uint32_t w = 0;
    #pragma unroll
    for (int t = 0; t < T_STEPS; ++t) {
        v = 0.5 * v + (double)x[t * BCN + idx];    // tau=2: v = v/2 + x
        if (v >= 1.0) { w |= (1u << (8 * t)); v = 0.0; }  // spike + hard reset
    }
    sp[idx] = w;
}

// ---------------------------------------------------------------------------
// Kernel B: for each (bc, m): y1[t] = sum_n s[t,n]*w1[m,n] (fp32),
//           y2[t] = same with w2 but EXACT (fp64 adds of fp32 values, s in {0,1}),
//           then s3 = lif(y2) in fp64, z[t] = s3 ? y1[t] : 0.
// Block tile: 16 bc  x 64 m, all 4 t in-register per thread.
// Threads 256 = (tx:16 m-groups of 4) x (ty:16 bc). K chunked by 64.
// ---------------------------------------------------------------------------
__global__ __launch_bounds__(256) void y1y2_lif_kernel(
    const uint32_t* __restrict__ sp,   // [BC][NDIM] packed spikes
    const float* __restrict__ w1,      // [768][768] row-major (m,n)
    const float* __restrict__ w2,
    float* __restrict__ z)             // [T][BC][NDIM]
{
    __shared__ uint32_t sA[16][65];    // spikes tile: 16 bc x 64 n (padded)
    __shared__ float sW1t[64][68];     // w1 tile transposed: [n][m] (68 keeps 16B align)
    __shared__ float sW2t[64][68];

    const int mb  = blockIdx.x % (NDIM / 64);
    const int rb  = blockIdx.x / (NDIM / 64);
    const int tid = threadIdx.x;
    const int tx  = tid & 15;          // m group: 4 consecutive m
    const int ty  = tid >> 4;          // bc within tile
    const int m0  = mb * 64;
    const int r0  = rb * 16;

    double acc2[T_STEPS][4];
    float  acc1[T_STEPS][4];
    #pragma unroll
    for (int t = 0; t < T_STEPS; ++t)
        #pragma unroll
        for (int j = 0; j < 4; ++j) { acc2[t][j] = 0.0; acc1[t][j] = 0.0f; }

    for (int k0 = 0; k0 < NDIM; k0 += 64) {
        // stage spike words: 16x64 u32, 4 per thread, coalesced
        #pragma unroll
        for (int it = 0; it < 4; ++it) {
            int i = tid + it * 256;
            int rr = i >> 6, nn = i & 63;
            sA[rr][nn] = sp[(r0 + rr) * NDIM + k0 + nn];
        }
        // stage w1/w2 tiles transposed to [n][m] so inner loop reads float4
        #pragma unroll
        for (int it = 0; it < 4; ++it) {
            int i = tid + it * 256;            // 0..1023
            int mrow = i >> 4, c4 = (i & 15) << 2;
            float4 a = *(const float4*)&w1[(size_t)(m0 + mrow) * NDIM + k0 + c4];
            sW1t[c4 + 0][mrow] = a.x; sW1t[c4 + 1][mrow] = a.y;
            sW1t[c4 + 2][mrow] = a.z; sW1t[c4 + 3][mrow] = a.w;
            float4 b = *(const float4*)&w2[(size_t)(m0 + mrow) * NDIM + k0 + c4];
            sW2t[c4 + 0][mrow] = b.x; sW2t[c4 + 1][mrow] = b.y;
            sW2t[c4 + 2][mrow] = b.z; sW2t[c4 + 3][mrow] = b.w;
        }
        __syncthreads();

        for (int kk = 0; kk < 64; ++kk) {
            uint32_t sw = sA[ty][kk];
            if (sw) {
                float4 w1v = *(const float4*)&sW1t[kk][tx * 4];
                float4 w2v = *(const float4*)&sW2t[kk][tx * 4];
                #pragma unroll
                for (int t = 0; t < T_STEPS; ++t) {
                    if ((sw >> (8 * t)) & 1u) {
                        acc1[t][0] += w1v.x; acc1[t][1] += w1v.y;
                        acc1[t][2] += w1v.z; acc1[t][3] += w1v.w;
                        acc2[t][0] += (double)w2v.x; acc2[t][1] += (double)w2v.y;
                        acc2[t][2] += (double)w2v.z; acc2[t][3] += (double)w2v.w;
                    }
                }
            }
        }
        __syncthreads();
    }

    // fp64 LIF over t on y2; z = y1 * s3 (reuse acc1 as z)
    #pragma unroll
    for (int j = 0; j < 4; ++j) {
        double v = 0.0;
        #pragma unroll
        for (int t = 0; t < T_STEPS; ++t) {
            v = 0.5 * v + acc2[t][j];
            if (v >= 1.0) { v = 0.0; }          // spike: keep y1, reset v
            else          { acc1[t][j] = 0.0f; } // no spike: z = 0
        }
    }

    #pragma unroll
    for (int t = 0; t < T_STEPS; ++t) {
        float4 q = make_float4(acc1[t][0], acc1[t][1], acc1[t][2], acc1[t][3]);
        *(float4*)&z[(size_t)(t * BC + r0 + ty) * NDIM + m0 + tx * 4] = q;
    }
}

// ---------------------------------------------------------------------------
// Kernel C: out[r][m] = sum_n z[r][n] * w3[m][n], fp32. z is ~98.5% zeros ->
// cheap all-zero skip per 4-row group. Block tile 64 rows x 64 m.
// ---------------------------------------------------------------------------
__global__ __launch_bounds__(256) void out_gemm_kernel(
    const float* __restrict__ z, const float* __restrict__ w3,
    float* __restrict__ out)
{
    __shared__ float sZt[64][68];      // z tile transposed [n][row]
    __shared__ float sW3t[64][68];     // w3 tile transposed [n][m]

    const int mb  = blockIdx.x % (NDIM / 64);
    const int rb  = blockIdx.x / (NDIM / 64);
    const int tid = threadIdx.x;
    const int tx  = tid & 15;          // m group (4 m)
    const int ty  = tid >> 4;          // row group (4 rows)
    const int m0  = mb * 64;
    const int r0  = rb * 64;

    float acc[4][4];
    #pragma unroll
    for (int i = 0; i < 4; ++i)
        #pragma unroll
        for (int j = 0; j < 4; ++j) acc[i][j] = 0.0f;

    for (int k0 = 0; k0 < NDIM; k0 += 64) {
        #pragma unroll
        for (int it = 0; it < 4; ++it) {
            int i = tid + it * 256;
            int row = i >> 4, c4 = (i & 15) << 2;
            float4 a = *(const float4*)&z[(size_t)(r0 + row) * NDIM + k0 + c4];
            sZt[c4 + 0][row] = a.x; sZt[c4 + 1][row] = a.y;
            sZt[c4 + 2][row] = a.z; sZt[c4 + 3][row] = a.w;
            float4 b = *(const float4*)&w3[(size_t)(m0 + row) * NDIM + k0 + c4];
            sW3t[c4 + 0][row] = b.x; sW3t[c4 + 1][row] = b.y;
            sW3t[c4 + 2][row] = b.z; sW3t[c4 + 3][row] = b.w;
        }
        __syncthreads();

        for (int kk = 0; kk < 64; ++kk) {
            float4 zv = *(const float4*)&sZt[kk][ty * 4];
            if (zv.x != 0.0f || zv.y != 0.0f || zv.z != 0.0f || zv.w != 0.0f) {
                float4 wv = *(const float4*)&sW3t[kk][tx * 4];
                acc[0][0] += zv.x * wv.x; acc[0][1] += zv.x * wv.y;
                acc[0][2] += zv.x * wv.z; acc[0][3] += zv.x * wv.w;
                acc[1][0] += zv.y * wv.x; acc[1][1] += zv.y * wv.y;
                acc[1][2] += zv.y * wv.z; acc[1][3] += zv.y * wv.w;
                acc[2][0] += zv.z * wv.x; acc[2][1] += zv.z * wv.y;
                acc[2][2] += zv.z * wv.z; acc[2][3] += zv.z * wv.w;
                acc[3][0] += zv.w * wv.x; acc[3][1] += zv.w * wv.y;
                acc[3][2] += zv.w * wv.z; acc[3][3] += zv.w * wv.w;
            }
        }
        __syncthreads();
    }

    #pragma unroll
    for (int i = 0; i < 4; ++i) {
        float4 q = make_float4(acc[i][0], acc[i][1], acc[i][2], acc[i][3]);
        *(float4*)&out[(size_t)(r0 + ty * 4 + i) * NDIM + m0 + tx * 4] = q;
    }
}

// ---------------------------------------------------------------------------
extern "C" void kernel_launch(void* const* d_in, const int* in_sizes, int n_in,
                              void* d_out, int out_size, void* d_ws, size_t ws_size,
                              hipStream_t stream) {
    const float* x  = (const float*)d_in[0];
    const float* w1 = (const float*)d_in[1];
    const float* w2 = (const float*)d_in[2];
    const float* w3 = (const float*)d_in[3];
    float* out = (float*)d_out;

    // workspace layout: [0, BCN*4)            packed spikes (u32 per bc,n)
    //                   [BCN*4, +TBC*NDIM*4)  z (fp32)
    uint32_t* sp = (uint32_t*)d_ws;
    float*    z  = (float*)((char*)d_ws + (size_t)BCN * 4);

    lif_x_kernel<<<BCN / 256, 256, 0, stream>>>(x, sp);

    {
        dim3 grid((BC / 16) * (NDIM / 64));     // 392 * 12 = 4704
        y1y2_lif_kernel<<<grid, 256, 0, stream>>>(sp, w1, w2, z);
    }
    {
        dim3 grid((TBC / 64) * (NDIM / 64));    // 392 * 12 = 4704
        out_gemm_kernel<<<grid, 256, 0, stream>>>(z, w3, out);
    }
}

// Round 2
// 423.985 us; speedup vs baseline: 4.1439x; 4.1439x over previous
//
#include <hip/hip_runtime.h>
#include <stdint.h>

// Dims fixed by reference: x [T=4,B=32,C=196,N=768] fp32; w1,w2,w3 [768][768] fp32.
#define T_STEPS 4
#define BC      6272            // B*C
#define NDIM    768
#define TBC     (T_STEPS*BC)    // 25088
#define BCN     (BC*NDIM)

typedef unsigned short u16;
typedef __attribute__((ext_vector_type(8))) __bf16 bf16x8;
typedef __attribute__((ext_vector_type(4))) float f32x4;

#define MFMA16(a,b,c) __builtin_amdgcn_mfma_f32_16x16x32_bf16((a),(b),(c),0,0,0)

__device__ __forceinline__ u16 f2b(float f) {           // fp32 -> bf16 bits, RNE
    uint32_t u = __builtin_bit_cast(uint32_t, f);
    u += 0x7FFFu + ((u >> 16) & 1u);
    return (u16)(u >> 16);
}
__device__ __forceinline__ float b2f(u16 b) {
    uint32_t u = ((uint32_t)b) << 16;
    return __builtin_bit_cast(float, u);
}
__device__ __forceinline__ void gload16(const void* g, void* l) {
    // async global->LDS, 16B/lane; LDS dest = wave-uniform base + lane*16
    __builtin_amdgcn_global_load_lds((const __attribute__((address_space(1))) void*)g,
                                     (__attribute__((address_space(3))) void*)l,
                                     16, 0, 0);
}

// ---------------------------------------------------------------------------
// s = lif(x) in fp64; write spikes as bf16 {0,1} planes [t][bc][n].
// ---------------------------------------------------------------------------
__global__ __launch_bounds__(256) void lif_x_kernel(const float* __restrict__ x,
                                                    u16* __restrict__ s) {
    int idx = blockIdx.x * 256 + threadIdx.x;
    double v = 0.0;
    #pragma unroll
    for (int t = 0; t < T_STEPS; ++t) {
        v = 0.5 * v + (double)x[(size_t)t * BCN + idx];
        u16 sp = 0;
        if (v >= 1.0) { sp = 0x3F80u; v = 0.0; }   // bf16(1.0)
        s[(size_t)t * BCN + idx] = sp;
    }
}

// ---------------------------------------------------------------------------
// Weight prep: w1->bf16; w2->bf16 hi + bf16 lo (hi+lo ~ fp32-accurate); w3->bf16.
// ---------------------------------------------------------------------------
__global__ __launch_bounds__(256) void prep_w_kernel(
    const float* __restrict__ w1, const float* __restrict__ w2,
    const float* __restrict__ w3,
    u16* __restrict__ w1b, u16* __restrict__ w2h,
    u16* __restrict__ w2l, u16* __restrict__ w3b) {
    int i = blockIdx.x * 256 + threadIdx.x;        // 768*768 total
    w1b[i] = f2b(w1[i]);
    float w = w2[i];
    u16 h = f2b(w);
    w2h[i] = h;
    w2l[i] = f2b(w - b2f(h));
    w3b[i] = f2b(w3[i]);
}

// ---------------------------------------------------------------------------
// Kernel B: y1 = s@w1^T (bf16 MFMA), y2 = s@w2^T (split bf16 MFMA, ~fp32-exact),
// fp64 LIF over t on y2 with exact-recompute fallback near threshold,
// z = y1 * s3 written as bf16 [t*BC+bc][768].
// Block: bc tile 32 x m tile 64, 4 waves (one 16-wide m-slice each), all 4 t.
// LDS tiles XOR-swizzled (byte ^= (row&7)<<4) via pre-swizzled gload source.
// ---------------------------------------------------------------------------
#define MARGIN 5e-4

__global__ __launch_bounds__(256) void y12_kernel(
    const u16* __restrict__ s,       // [TBC][768] bf16 bits
    const u16* __restrict__ w1b, const u16* __restrict__ w2hb,
    const u16* __restrict__ w2lb,
    const float* __restrict__ w2,    // fp32, fallback only
    u16* __restrict__ z)             // [TBC][768] bf16 bits
{
    __shared__ u16 As[4 * 32 * 64];          // 16 KB: rows (t*32+bc) x 64k
    __shared__ u16 B1[64 * 64];              // 8 KB each: rows m x 64k
    __shared__ u16 B2h[64 * 64];
    __shared__ u16 B2l[64 * 64];

    const int tid  = threadIdx.x;
    const int lane = tid & 63;
    const int wid  = tid >> 6;
    const int mb   = blockIdx.x % (NDIM / 64);
    const int rb   = blockIdx.x / (NDIM / 64);
    const int m0   = mb * 64;
    const int bc0  = rb * 32;

    // ---- staging source pointers (10 chunks of 1KB per wave, 40 total) ----
    const int lrow  = lane >> 3;                       // row within 8-row chunk
    const int scolE = ((((lane & 7) << 4) ^ (lrow << 4)) >> 1); // swizzled src col (elems)
    const u16* gp[10];
    u16*       lp[10];
    #pragma unroll
    for (int c = 0; c < 10; ++c) {
        int chunk = wid * 10 + c;
        const u16* g; u16* l;
        if (chunk < 16) {                              // A: spikes, 128 rows
            int grow = chunk * 8 + lrow;               // 0..127 = t*32+bcl
            int t = grow >> 5, bcl = grow & 31;
            g = s + ((size_t)(t * BC + bc0 + bcl)) * NDIM + scolE;
            l = As + chunk * 512;
        } else if (chunk < 24) {                       // w1 tile, 64 rows
            int grow = (chunk - 16) * 8 + lrow;
            g = w1b + ((size_t)(m0 + grow)) * NDIM + scolE;
            l = B1 + (chunk - 16) * 512;
        } else if (chunk < 32) {
            int grow = (chunk - 24) * 8 + lrow;
            g = w2hb + ((size_t)(m0 + grow)) * NDIM + scolE;
            l = B2h + (chunk - 24) * 512;
        } else {
            int grow = (chunk - 32) * 8 + lrow;
            g = w2lb + ((size_t)(m0 + grow)) * NDIM + scolE;
            l = B2l + (chunk - 32) * 512;
        }
        gp[c] = g; lp[c] = l;
    }

    // ---- fragment read offsets (swizzled) ----
    const int swz = (lane & 7) << 4;                   // byte swizzle for this lane's rows
    const int cb  = (lane >> 4) << 4;                  // k-group byte col base
    const int colE0 = ((cb      ) ^ swz) >> 1;         // k2 = 0
    const int colE1 = ((cb | 64 ) ^ swz) >> 1;         // k2 = 32
    int aoff[4][2];
    #pragma unroll
    for (int t = 0; t < 4; ++t)
        #pragma unroll
        for (int rt = 0; rt < 2; ++rt)
            aoff[t][rt] = (t * 32 + rt * 16 + (lane & 15)) * 64;
    const int boff = (wid * 16 + (lane & 15)) * 64;

    f32x4 acc1[4][2], acc2[4][2];
    #pragma unroll
    for (int t = 0; t < 4; ++t)
        #pragma unroll
        for (int rt = 0; rt < 2; ++rt) {
            acc1[t][rt] = (f32x4){0.f, 0.f, 0.f, 0.f};
            acc2[t][rt] = (f32x4){0.f, 0.f, 0.f, 0.f};
        }

    for (int k0 = 0; k0 < NDIM; k0 += 64) {
        __syncthreads();                               // prev reads done
        #pragma unroll
        for (int c = 0; c < 10; ++c) { gload16(gp[c], lp[c]); gp[c] += 64; }
        __syncthreads();                               // loads landed (vmcnt drain)

        #pragma unroll
        for (int k2i = 0; k2i < 2; ++k2i) {
            const int ce = k2i ? colE1 : colE0;
            bf16x8 b1 = *(const bf16x8*)&B1 [boff + ce];
            bf16x8 bh = *(const bf16x8*)&B2h[boff + ce];
            bf16x8 bl = *(const bf16x8*)&B2l[boff + ce];
            #pragma unroll
            for (int t = 0; t < 4; ++t)
                #pragma unroll
                for (int rt = 0; rt < 2; ++rt) {
                    bf16x8 a = *(const bf16x8*)&As[aoff[t][rt] + ce];
                    acc1[t][rt] = MFMA16(a, b1, acc1[t][rt]);
                    acc2[t][rt] = MFMA16(a, bh, acc2[t][rt]);
                    acc2[t][rt] = MFMA16(a, bl, acc2[t][rt]);
                }
        }
    }

    // ---- epilogue: fp64 LIF on y2, fallback, z = y1*s3 ----
    const int mg = m0 + wid * 16 + (lane & 15);
    #pragma unroll
    for (int rt = 0; rt < 2; ++rt) {
        #pragma unroll
        for (int r = 0; r < 4; ++r) {
            const int bcg = bc0 + rt * 16 + (lane >> 4) * 4 + r;
            double v = 0.0;
            bool flag = false;
            float zv[4];
            #pragma unroll
            for (int t = 0; t < 4; ++t) {
                v = 0.5 * v + (double)acc2[t][rt][r];
                double d = v - 1.0;
                flag |= (d < MARGIN && d > -MARGIN);
                if (v >= 1.0) { zv[t] = acc1[t][rt][r]; v = 0.0; }
                else          { zv[t] = 0.0f; }
            }
            if (flag) {                                // exact fp64 recompute (rare)
                double y2e[4] = {0.0, 0.0, 0.0, 0.0};
                const float* w2row = w2 + (size_t)mg * NDIM;
                for (int n = 0; n < NDIM; ++n) {
                    double wv = (double)w2row[n];
                    #pragma unroll
                    for (int t = 0; t < 4; ++t)
                        if (s[((size_t)(t * BC + bcg)) * NDIM + n]) y2e[t] += wv;
                }
                v = 0.0;
                #pragma unroll
                for (int t = 0; t < 4; ++t) {
                    v = 0.5 * v + y2e[t];
                    if (v >= 1.0) { zv[t] = acc1[t][rt][r]; v = 0.0; }
                    else          { zv[t] = 0.0f; }
                }
            }
            #pragma unroll
            for (int t = 0; t < 4; ++t)
                z[((size_t)(t * BC + bcg)) * NDIM + mg] = f2b(zv[t]);
        }
    }
}

// ---------------------------------------------------------------------------
// Kernel C: out[r][m] = sum_n z[r][n]*w3[m][n], bf16 MFMA, fp32 out.
// Block: 64 rows x 64 m, 4 waves (16-wide m-slice each, all 64 rows).
// ---------------------------------------------------------------------------
__global__ __launch_bounds__(256) void out_kernel(
    const u16* __restrict__ z, const u16* __restrict__ w3b,
    float* __restrict__ out)
{
    __shared__ u16 Zs[64 * 64];
    __shared__ u16 Ws[64 * 64];

    const int tid  = threadIdx.x;
    const int lane = tid & 63;
    const int wid  = tid >> 6;
    const int mb   = blockIdx.x % (NDIM / 64);
    const int rb   = blockIdx.x / (NDIM / 64);
    const int m0   = mb * 64;
    const int r0   = rb * 64;

    const int lrow  = lane >> 3;
    const int scolE = ((((lane & 7) << 4) ^ (lrow << 4)) >> 1);
    const u16* gp[4];
    u16*       lp[4];
    #pragma unroll
    for (int c = 0; c < 4; ++c) {
        int chunk = wid * 4 + c;
        const u16* g; u16* l;
        if (chunk < 8) {
            int grow = chunk * 8 + lrow;
            g = z + ((size_t)(r0 + grow)) * NDIM + scolE;
            l = Zs + chunk * 512;
        } else {
            int grow = (chunk - 8) * 8 + lrow;
            g = w3b + ((size_t)(m0 + grow)) * NDIM + scolE;
            l = Ws + (chunk - 8) * 512;
        }
        gp[c] = g; lp[c] = l;
    }

    const int swz = (lane & 7) << 4;
    const int cb  = (lane >> 4) << 4;
    const int colE0 = ((cb     ) ^ swz) >> 1;
    const int colE1 = ((cb | 64) ^ swz) >> 1;
    const int boff = (wid * 16 + (lane & 15)) * 64;

    f32x4 acc[4];
    #pragma unroll
    for (int rt = 0; rt < 4; ++rt) acc[rt] = (f32x4){0.f, 0.f, 0.f, 0.f};

    for (int k0 = 0; k0 < NDIM; k0 += 64) {
        __syncthreads();
        #pragma unroll
        for (int c = 0; c < 4; ++c) { gload16(gp[c], lp[c]); gp[c] += 64; }
        __syncthreads();

        #pragma unroll
        for (int k2i = 0; k2i < 2; ++k2i) {
            const int ce = k2i ? colE1 : colE0;
            bf16x8 bw = *(const bf16x8*)&Ws[boff + ce];
            #pragma unroll
            for (int rt = 0; rt < 4; ++rt) {
                bf16x8 az = *(const bf16x8*)&Zs[(rt * 16 + (lane & 15)) * 64 + ce];
                acc[rt] = MFMA16(az, bw, acc[rt]);
            }
        }
    }

    #pragma unroll
    for (int rt = 0; rt < 4; ++rt)
        #pragma unroll
        for (int r = 0; r < 4; ++r)
            out[((size_t)(r0 + rt * 16 + (lane >> 4) * 4 + r)) * NDIM
                + m0 + wid * 16 + (lane & 15)] = acc[rt][r];
}

// ---------------------------------------------------------------------------
extern "C" void kernel_launch(void* const* d_in, const int* in_sizes, int n_in,
                              void* d_out, int out_size, void* d_ws, size_t ws_size,
                              hipStream_t stream) {
    const float* x  = (const float*)d_in[0];
    const float* w1 = (const float*)d_in[1];
    const float* w2 = (const float*)d_in[2];
    const float* w3 = (const float*)d_in[3];
    float* out = (float*)d_out;

    // workspace layout (bytes):
    //   s    [TBC*768] bf16 : 0            .. 38,535,168
    //   z    [TBC*768] bf16 : 38,535,168   .. 77,070,336
    //   w1b  [768^2]  bf16  : 77,070,336
    //   w2h  [768^2]  bf16  : 78,249,984
    //   w2l  [768^2]  bf16  : 79,429,632
    //   w3b  [768^2]  bf16  : 80,609,280   .. 81,788,928  (< ws used last round)
    char* ws = (char*)d_ws;
    u16* s   = (u16*)(ws);
    u16* z   = (u16*)(ws + 38535168);
    u16* w1b = (u16*)(ws + 77070336);
    u16* w2h = (u16*)(ws + 78249984);
    u16* w2l = (u16*)(ws + 79429632);
    u16* w3b = (u16*)(ws + 80609280);

    prep_w_kernel<<<(NDIM * NDIM) / 256, 256, 0, stream>>>(w1, w2, w3, w1b, w2h, w2l, w3b);
    lif_x_kernel<<<BCN / 256, 256, 0, stream>>>(x, s);
    y12_kernel<<<(BC / 32) * (NDIM / 64), 256, 0, stream>>>(s, w1b, w2h, w2l, w2, z);
    out_kernel<<<(TBC / 64) * (NDIM / 64), 256, 0, stream>>>(z, w3b, out);
}

// Round 3
// 164.633 us; speedup vs baseline: 10.6721x; 2.5753x over previous
//
#include <hip/hip_runtime.h>
#include <stdint.h>

// Dims fixed by reference: x [T=4,B=32,C=196,N=768] fp32; w1,w2,w3 [768][768] fp32.
#define T_STEPS 4
#define BC      6272            // B*C
#define NDIM    768
#define TBC     (T_STEPS*BC)    // 25088
#define BCN     (BC*NDIM)
#define FIX_CAP 65536
#define MARGIN  1e-4

typedef unsigned short u16;
typedef __attribute__((ext_vector_type(8))) __bf16 bf16x8;
typedef __attribute__((ext_vector_type(4))) float f32x4;

#define MFMA16(a,b,c) __builtin_amdgcn_mfma_f32_16x16x32_bf16((a),(b),(c),0,0,0)

__device__ __forceinline__ u16 f2b(float f) {           // fp32 -> bf16 bits, RNE
    uint32_t u = __builtin_bit_cast(uint32_t, f);
    u += 0x7FFFu + ((u >> 16) & 1u);
    return (u16)(u >> 16);
}
__device__ __forceinline__ float b2f(u16 b) {
    uint32_t u = ((uint32_t)b) << 16;
    return __builtin_bit_cast(float, u);
}
__device__ __forceinline__ void gload16(const void* g, void* l) {
    // async global->LDS, 16B/lane; LDS dest = wave-uniform base + lane*16
    __builtin_amdgcn_global_load_lds((const __attribute__((address_space(1))) void*)g,
                                     (__attribute__((address_space(3))) void*)l,
                                     16, 0, 0);
}

// ---------------------------------------------------------------------------
// s = lif(x) in fp64; spikes as bf16 {0,1} planes [t][bc][n].
// ---------------------------------------------------------------------------
__global__ __launch_bounds__(256) void lif_x_kernel(const float* __restrict__ x,
                                                    u16* __restrict__ s) {
    int idx = blockIdx.x * 256 + threadIdx.x;
    double v = 0.0;
    #pragma unroll
    for (int t = 0; t < T_STEPS; ++t) {
        v = 0.5 * v + (double)x[(size_t)t * BCN + idx];
        u16 sp = 0;
        if (v >= 1.0) { sp = 0x3F80u; v = 0.0; }   // bf16(1.0)
        s[(size_t)t * BCN + idx] = sp;
    }
}

// ---------------------------------------------------------------------------
// Weight prep: w1->bf16; w2->bf16 hi+lo; w3->bf16. Also zero the fixup counter.
// ---------------------------------------------------------------------------
__global__ __launch_bounds__(256) void prep_w_kernel(
    const float* __restrict__ w1, const float* __restrict__ w2,
    const float* __restrict__ w3,
    u16* __restrict__ w1b, u16* __restrict__ w2h,
    u16* __restrict__ w2l, u16* __restrict__ w3b,
    uint32_t* __restrict__ fix_cnt) {
    int i = blockIdx.x * 256 + threadIdx.x;
    if (i == 0) *fix_cnt = 0;
    w1b[i] = f2b(w1[i]);
    float w = w2[i];
    u16 h = f2b(w);
    w2h[i] = h;
    w2l[i] = f2b(w - b2f(h));
    w3b[i] = f2b(w3[i]);
}

// ---------------------------------------------------------------------------
// Kernel B: y1 = s@w1^T (bf16 MFMA), y2 = s@w2^T (split-bf16 MFMA, ~1e-5 exact),
// fp64 LIF on y2; near-threshold (bc,m) pairs pushed to a fixup list.
// z = y1 * s3 as bf16 [t*BC+bc][768].
// 2-phase double-buffered LDS (stage next tile before computing current);
// XOR-swizzled tiles via pre-swizzled gload source; XCD-chunked block swizzle.
// ---------------------------------------------------------------------------
__global__ __launch_bounds__(256) void y12_kernel(
    const u16* __restrict__ s,
    const u16* __restrict__ w1b, const u16* __restrict__ w2hb,
    const u16* __restrict__ w2lb,
    u16* __restrict__ z,
    uint32_t* __restrict__ fix_cnt,
    int2* __restrict__ fix_idx, float4* __restrict__ fix_y1)
{
    // per-buffer flat LDS layout (u16 elems): As [0,8192) B1 [8192,12288)
    // B2h [12288,16384) B2l [16384,20480); 40KB x 2 buffers = 80KB
    __shared__ u16 lds[2][20480];

    const int tid  = threadIdx.x;
    const int lane = tid & 63;
    const int wid  = tid >> 6;

    // XCD-chunked swizzle: nwg = 2352 = 8 * 294
    const int bid = blockIdx.x;
    const int swz = (bid & 7) * 294 + (bid >> 3);
    const int mb  = swz % (NDIM / 64);
    const int rb  = swz / (NDIM / 64);
    const int m0  = mb * 64;
    const int bc0 = rb * 32;

    // ---- staging: 40 chunks of 512 elems (1KB); 10 per wave ----
    const int lrow  = lane >> 3;
    const int scolE = ((((lane & 7) << 4) ^ (lrow << 4)) >> 1); // swizzled src col
    const u16* gp[10];
    int lofs[10];
    #pragma unroll
    for (int c = 0; c < 10; ++c) {
        int chunk = wid * 10 + c;
        const u16* g;
        if (chunk < 16) {                              // A: 128 rows = t*32+bcl
            int grow = chunk * 8 + lrow;
            int t = grow >> 5, bcl = grow & 31;
            g = s + ((size_t)(t * BC + bc0 + bcl)) * NDIM + scolE;
        } else if (chunk < 24) {
            int grow = (chunk - 16) * 8 + lrow;
            g = w1b + ((size_t)(m0 + grow)) * NDIM + scolE;
        } else if (chunk < 32) {
            int grow = (chunk - 24) * 8 + lrow;
            g = w2hb + ((size_t)(m0 + grow)) * NDIM + scolE;
        } else {
            int grow = (chunk - 32) * 8 + lrow;
            g = w2lb + ((size_t)(m0 + grow)) * NDIM + scolE;
        }
        gp[c] = g;
        lofs[c] = chunk * 512;
    }

    // ---- fragment read offsets (swizzled) ----
    const int swzb = (lane & 7) << 4;
    const int cb   = (lane >> 4) << 4;
    const int colE0 = ((cb     ) ^ swzb) >> 1;
    const int colE1 = ((cb | 64) ^ swzb) >> 1;
    int aoff[4][2];
    #pragma unroll
    for (int t = 0; t < 4; ++t)
        #pragma unroll
        for (int rt = 0; rt < 2; ++rt)
            aoff[t][rt] = (t * 32 + rt * 16 + (lane & 15)) * 64;
    const int boff = (wid * 16 + (lane & 15)) * 64;

    f32x4 acc1[4][2], acc2[4][2];
    #pragma unroll
    for (int t = 0; t < 4; ++t)
        #pragma unroll
        for (int rt = 0; rt < 2; ++rt) {
            acc1[t][rt] = (f32x4){0.f, 0.f, 0.f, 0.f};
            acc2[t][rt] = (f32x4){0.f, 0.f, 0.f, 0.f};
        }

    auto stage = [&](int buf) {
        #pragma unroll
        for (int c = 0; c < 10; ++c) {
            gload16(gp[c], &lds[buf][lofs[c]]);
            gp[c] += 64;
        }
    };
    auto compute = [&](int buf) {
        const u16* L = lds[buf];
        #pragma unroll
        for (int k2i = 0; k2i < 2; ++k2i) {
            const int ce = k2i ? colE1 : colE0;
            bf16x8 b1 = *(const bf16x8*)&L[ 8192 + boff + ce];
            bf16x8 bh = *(const bf16x8*)&L[12288 + boff + ce];
            bf16x8 bl = *(const bf16x8*)&L[16384 + boff + ce];
            #pragma unroll
            for (int t = 0; t < 4; ++t)
                #pragma unroll
                for (int rt = 0; rt < 2; ++rt) {
                    bf16x8 a = *(const bf16x8*)&L[aoff[t][rt] + ce];
                    acc1[t][rt] = MFMA16(a, b1, acc1[t][rt]);
                    acc2[t][rt] = MFMA16(a, bh, acc2[t][rt]);
                    acc2[t][rt] = MFMA16(a, bl, acc2[t][rt]);
                }
        }
    };

    // ---- 2-phase pipeline: stage(next) -> compute(cur) -> drain+barrier ----
    stage(0);
    __syncthreads();
    for (int it = 0; it < 11; ++it) {
        int bufc = it & 1;
        stage(bufc ^ 1);
        compute(bufc);
        __syncthreads();            // drains vmcnt(0) for next tile + lgkm
    }
    compute(1);

    // ---- epilogue: fp64 LIF on y2, flag near-threshold to list, z = y1*s3 ----
    const int mg = m0 + wid * 16 + (lane & 15);
    #pragma unroll
    for (int rt = 0; rt < 2; ++rt) {
        #pragma unroll
        for (int r = 0; r < 4; ++r) {
            const int bcg = bc0 + rt * 16 + (lane >> 4) * 4 + r;
            double v = 0.0;
            bool flag = false;
            float zv[4];
            #pragma unroll
            for (int t = 0; t < 4; ++t) {
                v = 0.5 * v + (double)acc2[t][rt][r];
                double d = v - 1.0;
                flag |= (d < MARGIN && d > -MARGIN);
                if (v >= 1.0) { zv[t] = acc1[t][rt][r]; v = 0.0; }
                else          { zv[t] = 0.0f; }
            }
            if (flag) {
                uint32_t id = atomicAdd(fix_cnt, 1u);
                if (id < FIX_CAP) {
                    fix_idx[id] = make_int2(bcg, mg);
                    fix_y1[id]  = make_float4(acc1[0][rt][r], acc1[1][rt][r],
                                              acc1[2][rt][r], acc1[3][rt][r]);
                }
            }
            #pragma unroll
            for (int t = 0; t < 4; ++t)
                z[((size_t)(t * BC + bcg)) * NDIM + mg] = f2b(zv[t]);
        }
    }
}

// ---------------------------------------------------------------------------
// Exact fp64 recompute of flagged (bc,m) pairs; one wave per entry.
// ---------------------------------------------------------------------------
__global__ __launch_bounds__(256) void fixup_kernel(
    const u16* __restrict__ s, const float* __restrict__ w2,
    const int2* __restrict__ fix_idx, const float4* __restrict__ fix_y1,
    const uint32_t* __restrict__ fix_cnt, u16* __restrict__ z)
{
    const int lane = threadIdx.x & 63;
    const int wave = (blockIdx.x * 256 + threadIdx.x) >> 6;
    const int nw   = gridDim.x * 4;
    uint32_t n = *fix_cnt;
    if (n > FIX_CAP) n = FIX_CAP;

    for (uint32_t e = wave; e < n; e += nw) {
        const int bc = fix_idx[e].x, m = fix_idx[e].y;
        const float* w2row = w2 + (size_t)m * NDIM;
        double acc[4] = {0.0, 0.0, 0.0, 0.0};
        #pragma unroll
        for (int j = 0; j < NDIM / 64; ++j) {
            int nn = lane + j * 64;
            double wv = (double)w2row[nn];
            #pragma unroll
            for (int t = 0; t < 4; ++t)
                if (s[((size_t)(t * BC + bc)) * NDIM + nn]) acc[t] += wv;
        }
        #pragma unroll
        for (int o = 32; o > 0; o >>= 1)
            #pragma unroll
            for (int t = 0; t < 4; ++t) acc[t] += __shfl_xor(acc[t], o);
        if (lane == 0) {
            float4 y1 = fix_y1[e];
            float y1a[4] = {y1.x, y1.y, y1.z, y1.w};
            double v = 0.0;
            #pragma unroll
            for (int t = 0; t < 4; ++t) {
                v = 0.5 * v + acc[t];
                u16 zz = 0;
                if (v >= 1.0) { zz = f2b(y1a[t]); v = 0.0; }
                z[((size_t)(t * BC + bc)) * NDIM + m] = zz;
            }
        }
    }
}

// ---------------------------------------------------------------------------
// Kernel C: out[r][m] = sum_n z[r][n]*w3[m][n], bf16 MFMA, fp32 out.
// Same 2-phase dbuf structure. Block 64 rows x 64 m, 4 waves.
// ---------------------------------------------------------------------------
__global__ __launch_bounds__(256) void out_kernel(
    const u16* __restrict__ z, const u16* __restrict__ w3b,
    float* __restrict__ out)
{
    // per-buffer: Zs [0,4096) Ws [4096,8192); 16KB x 2 = 32KB
    __shared__ u16 lds[2][8192];

    const int tid  = threadIdx.x;
    const int lane = tid & 63;
    const int wid  = tid >> 6;

    // XCD-chunked swizzle: nwg = 4704 = 8 * 588
    const int bid = blockIdx.x;
    const int swz = (bid & 7) * 588 + (bid >> 3);
    const int mb  = swz % (NDIM / 64);
    const int rb  = swz / (NDIM / 64);
    const int m0  = mb * 64;
    const int r0  = rb * 64;

    const int lrow  = lane >> 3;
    const int scolE = ((((lane & 7) << 4) ^ (lrow << 4)) >> 1);
    const u16* gp[4];
    int lofs[4];
    #pragma unroll
    for (int c = 0; c < 4; ++c) {
        int chunk = wid * 4 + c;
        const u16* g;
        if (chunk < 8) {
            int grow = chunk * 8 + lrow;
            g = z + ((size_t)(r0 + grow)) * NDIM + scolE;
        } else {
            int grow = (chunk - 8) * 8 + lrow;
            g = w3b + ((size_t)(m0 + grow)) * NDIM + scolE;
        }
        gp[c] = g;
        lofs[c] = chunk * 512;
    }

    const int swzb = (lane & 7) << 4;
    const int cb   = (lane >> 4) << 4;
    const int colE0 = ((cb     ) ^ swzb) >> 1;
    const int colE1 = ((cb | 64) ^ swzb) >> 1;
    const int boff = (wid * 16 + (lane & 15)) * 64;

    f32x4 acc[4];
    #pragma unroll
    for (int rt = 0; rt < 4; ++rt) acc[rt] = (f32x4){0.f, 0.f, 0.f, 0.f};

    auto stage = [&](int buf) {
        #pragma unroll
        for (int c = 0; c < 4; ++c) {
            gload16(gp[c], &lds[buf][lofs[c]]);
            gp[c] += 64;
        }
    };
    auto compute = [&](int buf) {
        const u16* L = lds[buf];
        #pragma unroll
        for (int k2i = 0; k2i < 2; ++k2i) {
            const int ce = k2i ? colE1 : colE0;
            bf16x8 bw = *(const bf16x8*)&L[4096 + boff + ce];
            #pragma unroll
            for (int rt = 0; rt < 4; ++rt) {
                bf16x8 az = *(const bf16x8*)&L[(rt * 16 + (lane & 15)) * 64 + ce];
                acc[rt] = MFMA16(az, bw, acc[rt]);
            }
        }
    };

    stage(0);
    __syncthreads();
    for (int it = 0; it < 11; ++it) {
        int bufc = it & 1;
        stage(bufc ^ 1);
        compute(bufc);
        __syncthreads();
    }
    compute(1);

    #pragma unroll
    for (int rt = 0; rt < 4; ++rt)
        #pragma unroll
        for (int r = 0; r < 4; ++r)
            out[((size_t)(r0 + rt * 16 + (lane >> 4) * 4 + r)) * NDIM
                + m0 + wid * 16 + (lane & 15)] = acc[rt][r];
}

// ---------------------------------------------------------------------------
extern "C" void kernel_launch(void* const* d_in, const int* in_sizes, int n_in,
                              void* d_out, int out_size, void* d_ws, size_t ws_size,
                              hipStream_t stream) {
    const float* x  = (const float*)d_in[0];
    const float* w1 = (const float*)d_in[1];
    const float* w2 = (const float*)d_in[2];
    const float* w3 = (const float*)d_in[3];
    float* out = (float*)d_out;

    // workspace layout (bytes):
    char* ws = (char*)d_ws;
    u16*      s       = (u16*)(ws);                       // 38,535,168
    u16*      z       = (u16*)(ws + 38535168);            // 38,535,168
    u16*      w1b     = (u16*)(ws + 77070336);            // 1,179,648
    u16*      w2h     = (u16*)(ws + 78249984);
    u16*      w2l     = (u16*)(ws + 79429632);
    u16*      w3b     = (u16*)(ws + 80609280);
    uint32_t* fix_cnt = (uint32_t*)(ws + 81788928);
    int2*     fix_idx = (int2*)(ws + 81788992);           // 512KB
    float4*   fix_y1  = (float4*)(ws + 82313280);         // 1MB

    prep_w_kernel<<<(NDIM * NDIM) / 256, 256, 0, stream>>>(w1, w2, w3, w1b, w2h,
                                                           w2l, w3b, fix_cnt);
    lif_x_kernel<<<BCN / 256, 256, 0, stream>>>(x, s);
    y12_kernel<<<(BC / 32) * (NDIM / 64), 256, 0, stream>>>(s, w1b, w2h, w2l, z,
                                                            fix_cnt, fix_idx, fix_y1);
    fixup_kernel<<<128, 256, 0, stream>>>(s, w2, fix_idx, fix_y1, fix_cnt, z);
    out_kernel<<<(TBC / 64) * (NDIM / 64), 256, 0, stream>>>(z, w3b, out);
}